// Round 2
// baseline (12211.143 us; speedup 1.0000x reference)
//
#include <hip/hip_runtime.h>
#include <hip/hip_bf16.h>

#define NVV 100000
#define NCC 400000
#define NEE 1600000

typedef short short8 __attribute__((ext_vector_type(8)));
typedef short short4v __attribute__((ext_vector_type(4)));
typedef float f32x4 __attribute__((ext_vector_type(4)));

__device__ __forceinline__ float b2f(short s) {
    unsigned int u = ((unsigned int)(unsigned short)s) << 16;
    return __builtin_bit_cast(float, u);
}
__device__ __forceinline__ short f2b(float f) {
    __hip_bfloat16 h = __float2bfloat16(f);
    return __builtin_bit_cast(short, h);
}

// Fused 2-layer MLP: Out = relu(relu(X @ W1 + b1) @ W2 + b2)
// All global float tensors are f32; MFMA inputs converted to bf16, f32 accum.
// Computed transposed: D = (W^T as A-operand) x (X as B-operand):
// lane layout: col(lane&15)=X-row-in-tile, row(quad*4+i)=feature.
// TWO_SRC: columns [128,256) of X come from X2. OUT_BF16: write bf16 (scratch z).
template<int K1, int BM, bool TWO_SRC, bool OUT_BF16>
__global__ __launch_bounds__(BM * 2, 2)
void mlp2_fused(const float* __restrict__ X, const float* __restrict__ X2,
                const float* __restrict__ W1, const float* __restrict__ B1,
                const float* __restrict__ W2, const float* __restrict__ B2,
                void* __restrict__ OutP, int M)
{
    constexpr int PADK = K1 + 8;       // +16B pad: 2-way LDS conflicts only (free)
    constexpr int NT = BM * 2;         // threads (BM/32 waves, 32 rows/wave)
    __shared__ short sW[128 * PADK];   // W1^T bf16, then W2^T restaged
    __shared__ short sH[BM * 136];     // layer-1 activations bf16 [m][k2]

    const int tid = threadIdx.x;
    const int lane = tid & 63;
    const int w = tid >> 6;
    const int p = lane & 15;           // position within 16
    const int q = lane >> 4;           // quad
    const long rowBase = (long)blockIdx.x * BM;

    // ---- stage W1^T (cvt f32->bf16): sW[n*PADK + k] = bf16(W1[k*128 + n])
    for (int e = tid * 4; e < K1 * 128; e += NT * 4) {
        int k = e >> 7, n0 = e & 127;
        f32x4 v = *(const f32x4*)(W1 + e);
        #pragma unroll
        for (int j = 0; j < 4; ++j) sW[(n0 + j) * PADK + k] = f2b(v[j]);
    }

    // ---- preload X fragments (B-operand), cvt f32->bf16, row-clamped
    short8 xf[2][K1 / 32];
    #pragma unroll
    for (int t = 0; t < 2; ++t) {
        long m = rowBase + w * 32 + t * 16 + p;
        if (m > (long)M - 1) m = (long)M - 1;
        #pragma unroll
        for (int kk = 0; kk < K1 / 32; ++kk) {
            int k0 = kk * 32 + q * 8;
            const float* src;
            if (TWO_SRC && k0 >= 128) src = X2 + m * 128 + (k0 - 128);
            else                      src = X  + m * 128 + k0;
            f32x4 a = *(const f32x4*)(src);
            f32x4 b = *(const f32x4*)(src + 4);
            short8 s;
            #pragma unroll
            for (int j = 0; j < 4; ++j) { s[j] = f2b(a[j]); s[j + 4] = f2b(b[j]); }
            xf[t][kk] = s;
        }
    }

    __syncthreads();

    // ---- layer 1
    f32x4 acc[8][2];
    #pragma unroll
    for (int c = 0; c < 8; ++c)
        #pragma unroll
        for (int t = 0; t < 2; ++t)
            acc[c][t] = (f32x4){0.f, 0.f, 0.f, 0.f};

    #pragma unroll
    for (int kk = 0; kk < K1 / 32; ++kk) {
        short8 af[8];
        #pragma unroll
        for (int c = 0; c < 8; ++c)
            af[c] = *(const short8*)(sW + (c * 16 + p) * PADK + kk * 32 + q * 8);
        #pragma unroll
        for (int c = 0; c < 8; ++c)
            #pragma unroll
            for (int t = 0; t < 2; ++t)
                acc[c][t] = __builtin_amdgcn_mfma_f32_16x16x32_bf16(af[c], xf[t][kk], acc[c][t], 0, 0, 0);
    }

    // ---- bias + relu -> sH[m][n1] bf16 (8B vector stores)
    #pragma unroll
    for (int c = 0; c < 8; ++c) {
        f32x4 bb = *(const f32x4*)(B1 + c * 16 + q * 4);
        #pragma unroll
        for (int t = 0; t < 2; ++t) {
            short4v sv;
            #pragma unroll
            for (int i = 0; i < 4; ++i)
                sv[i] = f2b(fmaxf(acc[c][t][i] + bb[i], 0.f));
            *(short4v*)(sH + (w * 32 + t * 16 + p) * 136 + c * 16 + q * 4) = sv;
        }
    }

    __syncthreads();

    // ---- restage W2^T into sW (cvt f32->bf16)
    for (int e = tid * 4; e < 128 * 128; e += NT * 4) {
        int k = e >> 7, n0 = e & 127;
        f32x4 v = *(const f32x4*)(W2 + e);
        #pragma unroll
        for (int j = 0; j < 4; ++j) sW[(n0 + j) * PADK + k] = f2b(v[j]);
    }
    __syncthreads();

    // ---- layer 2
    f32x4 acc2[8][2];
    #pragma unroll
    for (int c = 0; c < 8; ++c)
        #pragma unroll
        for (int t = 0; t < 2; ++t)
            acc2[c][t] = (f32x4){0.f, 0.f, 0.f, 0.f};

    #pragma unroll
    for (int kk = 0; kk < 4; ++kk) {
        short8 af[8], bfr[2];
        #pragma unroll
        for (int c = 0; c < 8; ++c)
            af[c] = *(const short8*)(sW + (c * 16 + p) * PADK + kk * 32 + q * 8);
        #pragma unroll
        for (int t = 0; t < 2; ++t)
            bfr[t] = *(const short8*)(sH + (w * 32 + t * 16 + p) * 136 + kk * 32 + q * 8);
        #pragma unroll
        for (int c = 0; c < 8; ++c)
            #pragma unroll
            for (int t = 0; t < 2; ++t)
                acc2[c][t] = __builtin_amdgcn_mfma_f32_16x16x32_bf16(af[c], bfr[t], acc2[c][t], 0, 0, 0);
    }

    // ---- epilogue: bias + relu -> global
    #pragma unroll
    for (int c = 0; c < 8; ++c) {
        f32x4 bb = *(const f32x4*)(B2 + c * 16 + q * 4);
        #pragma unroll
        for (int t = 0; t < 2; ++t) {
            long m = rowBase + w * 32 + t * 16 + p;
            if (m < M) {
                if (OUT_BF16) {
                    short4v sv;
                    #pragma unroll
                    for (int i = 0; i < 4; ++i)
                        sv[i] = f2b(fmaxf(acc2[c][t][i] + bb[i], 0.f));
                    *(short4v*)((short*)OutP + m * 128 + c * 16 + q * 4) = sv;
                } else {
                    f32x4 fv;
                    #pragma unroll
                    for (int i = 0; i < 4; ++i)
                        fv[i] = fmaxf(acc2[c][t][i] + bb[i], 0.f);
                    *(f32x4*)((float*)OutP + m * 128 + c * 16 + q * 4) = fv;
                }
            }
        }
    }
}

// mv[rows[e]] += z[cols[e]]  (16 threads/edge, 8 cols each, f32 atomics, z is bf16)
__global__ __launch_bounds__(256)
void scatter_add(const short* __restrict__ z, const int* __restrict__ rows,
                 const int* __restrict__ cols, float* __restrict__ dst, int E)
{
    long tid = (long)blockIdx.x * 256 + threadIdx.x;
    if (tid >= (long)E * 16) return;
    int e = (int)(tid >> 4);
    int c8 = ((int)tid & 15) * 8;
    int r = rows[e];
    int c = cols[e];
    short8 v = *(const short8*)(z + (long)c * 128 + c8);
    float* d = dst + (long)r * 128 + c8;
    #pragma unroll
    for (int j = 0; j < 8; ++j) atomicAdd(d + j, b2f(v[j]));
}

extern "C" void kernel_launch(void* const* d_in, const int* in_sizes, int n_in,
                              void* d_out, int out_size, void* d_ws, size_t ws_size,
                              hipStream_t stream)
{
    const float* hv   = (const float*)d_in[0];
    const float* hc   = (const float*)d_in[1];
    const int* row_v  = (const int*)d_in[2];
    const int* col_v  = (const int*)d_in[3];
    const int* row_c  = (const int*)d_in[4];
    const int* col_c  = (const int*)d_in[5];
    const float* mw1  = (const float*)d_in[6];
    const float* mb1  = (const float*)d_in[7];
    const float* mw2  = (const float*)d_in[8];
    const float* mb2  = (const float*)d_in[9];
    const float* uw1  = (const float*)d_in[10];
    const float* ub1  = (const float*)d_in[11];
    const float* uw2  = (const float*)d_in[12];
    const float* ub2  = (const float*)d_in[13];
    float* out = (float*)d_out;

    // ws layout: zv bf16 [2*NC,128] | zc bf16 [2*NV,128] | mv f32 [NV,128] | mc f32 [NC,128]
    size_t zv_e = (size_t)2 * NCC * 128;
    size_t zc_e = (size_t)2 * NVV * 128;
    size_t mv_e = (size_t)NVV * 128;
    size_t mc_e = (size_t)NCC * 128;
    short* zv = (short*)d_ws;
    short* zc = zv + zv_e;
    float* mv = (float*)(zc + zc_e);
    float* mc = mv + mv_e;

    hipMemsetAsync(mv, 0, mv_e * 4, stream);
    hipMemsetAsync(mc, 0, mc_e * 4, stream);

    // message MLPs: zv = [fmv_pos(hc); fmv_neg(hc)], zc = [fmc_pos(hv); fmc_neg(hv)]
    mlp2_fused<128, 128, false, true><<<NCC / 128, 256, 0, stream>>>(
        hc, nullptr, mw1 + 0 * 16384, mb1 + 0 * 128, mw2 + 0 * 16384, mb2 + 0 * 128, zv, NCC);
    mlp2_fused<128, 128, false, true><<<NCC / 128, 256, 0, stream>>>(
        hc, nullptr, mw1 + 1 * 16384, mb1 + 1 * 128, mw2 + 1 * 16384, mb2 + 1 * 128,
        zv + (size_t)NCC * 128, NCC);
    mlp2_fused<128, 128, false, true><<<(NVV + 127) / 128, 256, 0, stream>>>(
        hv, nullptr, mw1 + 2 * 16384, mb1 + 2 * 128, mw2 + 2 * 16384, mb2 + 2 * 128, zc, NVV);
    mlp2_fused<128, 128, false, true><<<(NVV + 127) / 128, 256, 0, stream>>>(
        hv, nullptr, mw1 + 3 * 16384, mb1 + 3 * 128, mw2 + 3 * 16384, mb2 + 3 * 128,
        zc + (size_t)NVV * 128, NVV);

    // segment sums via f32 atomics
    scatter_add<<<(int)((size_t)NEE * 16 / 256), 256, 0, stream>>>(zv, row_v, col_v, mv, NEE);
    scatter_add<<<(int)((size_t)NEE * 16 / 256), 256, 0, stream>>>(zc, row_c, col_c, mc, NEE);

    // update MLPs: concat(h, m) -> K1=256
    mlp2_fused<256, 256, true, false><<<(NVV + 255) / 256, 512, 0, stream>>>(
        hv, mv, uw1 + 0 * 32768, ub1 + 0 * 128, uw2 + 0 * 16384, ub2 + 0 * 128, out, NVV);
    mlp2_fused<256, 256, true, false><<<(NCC + 255) / 256, 512, 0, stream>>>(
        hc, mc, uw1 + 1 * 32768, ub1 + 1 * 128, uw2 + 1 * 16384, ub2 + 1 * 128,
        out + (size_t)NVV * 128, NCC);
}

// Round 3
// 1654.060 us; speedup vs baseline: 7.3825x; 7.3825x over previous
//
#include <hip/hip_runtime.h>
#include <hip/hip_bf16.h>

#define NVV 100000
#define NCC 400000
#define NEE 1600000

typedef short short8 __attribute__((ext_vector_type(8)));
typedef short short4v __attribute__((ext_vector_type(4)));
typedef float f32x4 __attribute__((ext_vector_type(4)));

__device__ __forceinline__ float b2f(short s) {
    unsigned int u = ((unsigned int)(unsigned short)s) << 16;
    return __builtin_bit_cast(float, u);
}
__device__ __forceinline__ short f2b(float f) {
    __hip_bfloat16 h = __float2bfloat16(f);
    return __builtin_bit_cast(short, h);
}

// Fused 2-layer MLP: Out = relu(relu(X @ W1 + b1) @ W2 + b2)
// X/weights f32 in HBM; MFMA inputs bf16, f32 accum.
// Transposed compute: D = (W^T as A) x (X as B); col(lane&15)=row-of-X, row(quad*4+i)=feature.
// TWO_SRC: cols [128,256) of the input come from X2 (bf16). OUT_BF16: write bf16 scratch.
template<int K1, int BM, bool TWO_SRC, bool OUT_BF16>
__global__ __launch_bounds__(BM * 2, 2)
void mlp2_fused(const float* __restrict__ X, const short* __restrict__ X2,
                const float* __restrict__ W1, const float* __restrict__ B1,
                const float* __restrict__ W2, const float* __restrict__ B2,
                void* __restrict__ OutP, int M)
{
    constexpr int PADK = K1 + 8;
    constexpr int NT = BM * 2;
    __shared__ short sW[128 * PADK];   // W1^T bf16, then W2^T restaged
    __shared__ short sH[BM * 136];     // layer-1 activations bf16

    const int tid = threadIdx.x;
    const int lane = tid & 63;
    const int w = tid >> 6;
    const int p = lane & 15;
    const int q = lane >> 4;
    const long rowBase = (long)blockIdx.x * BM;

    for (int e = tid * 4; e < K1 * 128; e += NT * 4) {
        int k = e >> 7, n0 = e & 127;
        f32x4 v = *(const f32x4*)(W1 + e);
        #pragma unroll
        for (int j = 0; j < 4; ++j) sW[(n0 + j) * PADK + k] = f2b(v[j]);
    }

    short8 xf[2][K1 / 32];
    #pragma unroll
    for (int t = 0; t < 2; ++t) {
        long m = rowBase + w * 32 + t * 16 + p;
        if (m > (long)M - 1) m = (long)M - 1;
        #pragma unroll
        for (int kk = 0; kk < K1 / 32; ++kk) {
            int k0 = kk * 32 + q * 8;
            if (TWO_SRC && k0 >= 128) {
                xf[t][kk] = *(const short8*)(X2 + m * 128 + (k0 - 128));
            } else {
                const float* src = X + m * 128 + k0;
                f32x4 a = *(const f32x4*)(src);
                f32x4 b = *(const f32x4*)(src + 4);
                short8 s;
                #pragma unroll
                for (int j = 0; j < 4; ++j) { s[j] = f2b(a[j]); s[j + 4] = f2b(b[j]); }
                xf[t][kk] = s;
            }
        }
    }

    __syncthreads();

    f32x4 acc[8][2];
    #pragma unroll
    for (int c = 0; c < 8; ++c)
        #pragma unroll
        for (int t = 0; t < 2; ++t)
            acc[c][t] = (f32x4){0.f, 0.f, 0.f, 0.f};

    #pragma unroll
    for (int kk = 0; kk < K1 / 32; ++kk) {
        short8 af[8];
        #pragma unroll
        for (int c = 0; c < 8; ++c)
            af[c] = *(const short8*)(sW + (c * 16 + p) * PADK + kk * 32 + q * 8);
        #pragma unroll
        for (int c = 0; c < 8; ++c)
            #pragma unroll
            for (int t = 0; t < 2; ++t)
                acc[c][t] = __builtin_amdgcn_mfma_f32_16x16x32_bf16(af[c], xf[t][kk], acc[c][t], 0, 0, 0);
    }

    #pragma unroll
    for (int c = 0; c < 8; ++c) {
        f32x4 bb = *(const f32x4*)(B1 + c * 16 + q * 4);
        #pragma unroll
        for (int t = 0; t < 2; ++t) {
            short4v sv;
            #pragma unroll
            for (int i = 0; i < 4; ++i)
                sv[i] = f2b(fmaxf(acc[c][t][i] + bb[i], 0.f));
            *(short4v*)(sH + (w * 32 + t * 16 + p) * 136 + c * 16 + q * 4) = sv;
        }
    }

    __syncthreads();

    for (int e = tid * 4; e < 128 * 128; e += NT * 4) {
        int k = e >> 7, n0 = e & 127;
        f32x4 v = *(const f32x4*)(W2 + e);
        #pragma unroll
        for (int j = 0; j < 4; ++j) sW[(n0 + j) * PADK + k] = f2b(v[j]);
    }
    __syncthreads();

    f32x4 acc2[8][2];
    #pragma unroll
    for (int c = 0; c < 8; ++c)
        #pragma unroll
        for (int t = 0; t < 2; ++t)
            acc2[c][t] = (f32x4){0.f, 0.f, 0.f, 0.f};

    #pragma unroll
    for (int kk = 0; kk < 4; ++kk) {
        short8 af[8], bfr[2];
        #pragma unroll
        for (int c = 0; c < 8; ++c)
            af[c] = *(const short8*)(sW + (c * 16 + p) * PADK + kk * 32 + q * 8);
        #pragma unroll
        for (int t = 0; t < 2; ++t)
            bfr[t] = *(const short8*)(sH + (w * 32 + t * 16 + p) * 136 + kk * 32 + q * 8);
        #pragma unroll
        for (int c = 0; c < 8; ++c)
            #pragma unroll
            for (int t = 0; t < 2; ++t)
                acc2[c][t] = __builtin_amdgcn_mfma_f32_16x16x32_bf16(af[c], bfr[t], acc2[c][t], 0, 0, 0);
    }

    #pragma unroll
    for (int c = 0; c < 8; ++c) {
        f32x4 bb = *(const f32x4*)(B2 + c * 16 + q * 4);
        #pragma unroll
        for (int t = 0; t < 2; ++t) {
            long m = rowBase + w * 32 + t * 16 + p;
            if (m < M) {
                if (OUT_BF16) {
                    short4v sv;
                    #pragma unroll
                    for (int i = 0; i < 4; ++i)
                        sv[i] = f2b(fmaxf(acc2[c][t][i] + bb[i], 0.f));
                    *(short4v*)((short*)OutP + m * 128 + c * 16 + q * 4) = sv;
                } else {
                    f32x4 fv;
                    #pragma unroll
                    for (int i = 0; i < 4; ++i)
                        fv[i] = fmaxf(acc2[c][t][i] + bb[i], 0.f);
                    *(f32x4*)((float*)OutP + m * 128 + c * 16 + q * 4) = fv;
                }
            }
        }
    }
}

// ---------------- CSR build ----------------

__global__ __launch_bounds__(256)
void hist_kernel(const int* __restrict__ rows, int* __restrict__ counts, int E)
{
    int e = blockIdx.x * 256 + threadIdx.x;
    if (e < E) atomicAdd(&counts[rows[e]], 1);
}

// block b sums counts[b*512 .. b*512+512) -> bsum[b]
__global__ __launch_bounds__(256)
void seg_reduce(const int* __restrict__ counts, int* __restrict__ bsum, int N)
{
    __shared__ int s[256];
    int b = blockIdx.x, t = threadIdx.x;
    int base = b * 512;
    int v = 0;
    if (base + t < N) v += counts[base + t];
    if (base + 256 + t < N) v += counts[base + 256 + t];
    s[t] = v;
    __syncthreads();
    for (int off = 128; off > 0; off >>= 1) {
        if (t < off) s[t] += s[t + off];
        __syncthreads();
    }
    if (t == 0) bsum[b] = s[0];
}

// single block: exclusive scan of bsum[0..B), B <= 1024
__global__ __launch_bounds__(1024)
void scan_bsum(int* __restrict__ bsum, int B)
{
    __shared__ int s[1024];
    int t = threadIdx.x;
    s[t] = (t < B) ? bsum[t] : 0;
    __syncthreads();
    for (int off = 1; off < 1024; off <<= 1) {
        int v = (t >= off) ? s[t - off] : 0;
        __syncthreads();
        s[t] += v;
        __syncthreads();
    }
    if (t < B) bsum[t] = (t == 0) ? 0 : s[t - 1];
}

// block b: exclusive-scan its 512-chunk of counts, add bsum[b], write offs; offs[N]=total
__global__ __launch_bounds__(512)
void scan_final(const int* __restrict__ counts, const int* __restrict__ bsum,
                int* __restrict__ offs, int N)
{
    __shared__ int s[512];
    int b = blockIdx.x, t = threadIdx.x;
    int idx = b * 512 + t;
    int c = (idx < N) ? counts[idx] : 0;
    s[t] = c;
    __syncthreads();
    for (int off = 1; off < 512; off <<= 1) {
        int v = (t >= off) ? s[t - off] : 0;
        __syncthreads();
        s[t] += v;
        __syncthreads();
    }
    if (idx < N) offs[idx] = bsum[b] + s[t] - c;
    if (idx == N - 1) offs[N] = bsum[b] + s[t];
}

__global__ __launch_bounds__(256)
void csr_fill(const int* __restrict__ rows, const int* __restrict__ cols,
              const int* __restrict__ offs, int* __restrict__ cursor,
              int* __restrict__ edgeCol, int E)
{
    int e = blockIdx.x * 256 + threadIdx.x;
    if (e >= E) return;
    int r = rows[e];
    int pos = offs[r] + atomicAdd(&cursor[r], 1);
    edgeCol[pos] = cols[e];
}

// one wave per destination row; lane handles features [2*lane, 2*lane+1]
__global__ __launch_bounds__(256)
void csr_gather(const short* __restrict__ z, const int* __restrict__ offs,
                const int* __restrict__ edgeCol, short* __restrict__ m, int N)
{
    int wave = (int)((blockIdx.x * 256 + threadIdx.x) >> 6);
    int lane = threadIdx.x & 63;
    if (wave >= N) return;
    int beg = offs[wave], end = offs[wave + 1];
    float a0 = 0.f, a1 = 0.f;
    int j = beg;
    for (; j + 1 < end; j += 2) {
        int c0 = edgeCol[j], c1 = edgeCol[j + 1];
        unsigned int v0 = *(const unsigned int*)(z + (long)c0 * 128 + lane * 2);
        unsigned int v1 = *(const unsigned int*)(z + (long)c1 * 128 + lane * 2);
        a0 += b2f((short)(v0 & 0xffff)) + b2f((short)(v1 & 0xffff));
        a1 += b2f((short)(v0 >> 16)) + b2f((short)(v1 >> 16));
    }
    if (j < end) {
        int c = edgeCol[j];
        unsigned int v = *(const unsigned int*)(z + (long)c * 128 + lane * 2);
        a0 += b2f((short)(v & 0xffff));
        a1 += b2f((short)(v >> 16));
    }
    unsigned int o = ((unsigned int)(unsigned short)f2b(a1) << 16) | (unsigned short)f2b(a0);
    *(unsigned int*)(m + (long)wave * 128 + lane * 2) = o;
}

extern "C" void kernel_launch(void* const* d_in, const int* in_sizes, int n_in,
                              void* d_out, int out_size, void* d_ws, size_t ws_size,
                              hipStream_t stream)
{
    const float* hv   = (const float*)d_in[0];
    const float* hc   = (const float*)d_in[1];
    const int* row_v  = (const int*)d_in[2];
    const int* col_v  = (const int*)d_in[3];
    const int* row_c  = (const int*)d_in[4];
    const int* col_c  = (const int*)d_in[5];
    const float* mw1  = (const float*)d_in[6];
    const float* mb1  = (const float*)d_in[7];
    const float* mw2  = (const float*)d_in[8];
    const float* mb2  = (const float*)d_in[9];
    const float* uw1  = (const float*)d_in[10];
    const float* ub1  = (const float*)d_in[11];
    const float* uw2  = (const float*)d_in[12];
    const float* ub2  = (const float*)d_in[13];
    float* out = (float*)d_out;

    // ws: zv bf16[2NC,128] | zc bf16[2NV,128] | mv bf16[NV,128] | mc bf16[NC,128] | int scratch
    short* zv = (short*)d_ws;
    short* zc = zv + (size_t)2 * NCC * 128;
    short* mv = zc + (size_t)2 * NVV * 128;
    short* mc = mv + (size_t)NVV * 128;
    int* edge_v = (int*)(mc + (size_t)NCC * 128);
    int* edge_c = edge_v + NEE;
    int* offs_v = edge_c + NEE;
    int* offs_c = offs_v + (NVV + 1);
    int* cnt_v  = offs_c + (NCC + 1);
    int* cnt_c  = cnt_v + NVV;
    int* bsum_v = cnt_c + NCC;
    int* bsum_c = bsum_v + 1024;

    const int Bv = (NVV + 511) / 512;   // 196
    const int Bc = (NCC + 511) / 512;   // 782

    // ---- CSR build (both graphs)
    hipMemsetAsync(cnt_v, 0, NVV * sizeof(int), stream);
    hipMemsetAsync(cnt_c, 0, NCC * sizeof(int), stream);
    hist_kernel<<<(NEE + 255) / 256, 256, 0, stream>>>(row_v, cnt_v, NEE);
    hist_kernel<<<(NEE + 255) / 256, 256, 0, stream>>>(row_c, cnt_c, NEE);
    seg_reduce<<<Bv, 256, 0, stream>>>(cnt_v, bsum_v, NVV);
    seg_reduce<<<Bc, 256, 0, stream>>>(cnt_c, bsum_c, NCC);
    scan_bsum<<<1, 1024, 0, stream>>>(bsum_v, Bv);
    scan_bsum<<<1, 1024, 0, stream>>>(bsum_c, Bc);
    scan_final<<<Bv, 512, 0, stream>>>(cnt_v, bsum_v, offs_v, NVV);
    scan_final<<<Bc, 512, 0, stream>>>(cnt_c, bsum_c, offs_c, NCC);
    hipMemsetAsync(cnt_v, 0, NVV * sizeof(int), stream);
    hipMemsetAsync(cnt_c, 0, NCC * sizeof(int), stream);
    csr_fill<<<(NEE + 255) / 256, 256, 0, stream>>>(row_v, col_v, offs_v, cnt_v, edge_v, NEE);
    csr_fill<<<(NEE + 255) / 256, 256, 0, stream>>>(row_c, col_c, offs_c, cnt_c, edge_c, NEE);

    // ---- message MLPs: zv = [fmv_pos(hc); fmv_neg(hc)], zc = [fmc_pos(hv); fmc_neg(hv)]
    mlp2_fused<128, 128, false, true><<<NCC / 128, 256, 0, stream>>>(
        hc, nullptr, mw1 + 0 * 16384, mb1 + 0 * 128, mw2 + 0 * 16384, mb2 + 0 * 128, zv, NCC);
    mlp2_fused<128, 128, false, true><<<NCC / 128, 256, 0, stream>>>(
        hc, nullptr, mw1 + 1 * 16384, mb1 + 1 * 128, mw2 + 1 * 16384, mb2 + 1 * 128,
        zv + (size_t)NCC * 128, NCC);
    mlp2_fused<128, 128, false, true><<<(NVV + 127) / 128, 256, 0, stream>>>(
        hv, nullptr, mw1 + 2 * 16384, mb1 + 2 * 128, mw2 + 2 * 16384, mb2 + 2 * 128, zc, NVV);
    mlp2_fused<128, 128, false, true><<<(NVV + 127) / 128, 256, 0, stream>>>(
        hv, nullptr, mw1 + 3 * 16384, mb1 + 3 * 128, mw2 + 3 * 16384, mb2 + 3 * 128,
        zc + (size_t)NVV * 128, NVV);

    // ---- segment sums via CSR gather (no atomics on the feature path)
    csr_gather<<<(NVV + 3) / 4, 256, 0, stream>>>(zv, offs_v, edge_v, mv, NVV);
    csr_gather<<<(NCC + 3) / 4, 256, 0, stream>>>(zc, offs_c, edge_c, mc, NCC);

    // ---- update MLPs: concat(h, m) -> K1=256
    mlp2_fused<256, 256, true, false><<<(NVV + 255) / 256, 512, 0, stream>>>(
        hv, mv, uw1 + 0 * 32768, ub1 + 0 * 128, uw2 + 0 * 16384, ub2 + 0 * 128, out, NVV);
    mlp2_fused<256, 256, true, false><<<(NCC + 255) / 256, 512, 0, stream>>>(
        hc, mc, uw1 + 1 * 32768, ub1 + 1 * 128, uw2 + 1 * 16384, ub2 + 1 * 128,
        out + (size_t)NVV * 128, NCC);
}